// Round 5
// baseline (476.118 us; speedup 1.0000x reference)
//
#include <hip/hip_runtime.h>
#include <cstdint>

#define BB 256
#define TT 1000
#define DD 256
#define SS 10
#define HH 64
#define CC 100

// ---------------------------------------------------------------------------
// Kernel 1: input projection  xp[b,t,h] = 2*(x[b,t,:] . W_ih[s(t),h,:] + bias)
// bias = b_ih + b_hh folded; factor 2 pre-scales for tanh's exp(2z) so the
// rnn chain skips the 2*z multiply.
// ---------------------------------------------------------------------------
__global__ __launch_bounds__(256) void proj_kernel(
    const float* __restrict__ x, const float* __restrict__ W_ih,
    const float* __restrict__ b_ih, const float* __restrict__ b_hh,
    float* __restrict__ xp) {
  __shared__ float As[64][68];
  __shared__ float Bs[64][68];
  const int s = blockIdx.y;
  const int r0 = blockIdx.x * 64;   // row within segment, r = b*CC + c
  const int tid = threadIdx.x;
  const int ty = tid >> 4, tx = tid & 15;
  const int ty4 = ty * 4, tx4 = tx * 4;
  float acc[4][4] = {{0.f, 0.f, 0.f, 0.f}};

  for (int kc = 0; kc < 4; ++kc) {
#pragma unroll
    for (int m = 0; m < 4; ++m) {
      int f = m * 256 + tid;
      int row = f >> 4, kq = f & 15;
      int r = r0 + row;
      int b = r / CC, c = r - b * CC;
      const float4 av = *(const float4*)(
          x + ((size_t)b * TT + s * CC + c) * DD + kc * 64 + kq * 4);
      *(float4*)&As[row][kq * 4] = av;
      const float4 wv = *(const float4*)(
          W_ih + ((size_t)s * HH + row) * DD + kc * 64 + kq * 4);
      *(float4*)&Bs[row][kq * 4] = wv;
    }
    __syncthreads();
#pragma unroll 4
    for (int k = 0; k < 64; k += 4) {
      float4 a[4], w[4];
#pragma unroll
      for (int i = 0; i < 4; ++i) a[i] = *(const float4*)&As[ty4 + i][k];
#pragma unroll
      for (int j = 0; j < 4; ++j) w[j] = *(const float4*)&Bs[tx4 + j][k];
#pragma unroll
      for (int i = 0; i < 4; ++i)
#pragma unroll
        for (int j = 0; j < 4; ++j)
          acc[i][j] += a[i].x * w[j].x + a[i].y * w[j].y +
                       a[i].z * w[j].z + a[i].w * w[j].w;
    }
    __syncthreads();
  }

  const float4 b1 = *(const float4*)(b_ih + s * HH + tx4);
  const float4 b2 = *(const float4*)(b_hh + s * HH + tx4);
#pragma unroll
  for (int i = 0; i < 4; ++i) {
    int r = r0 + ty4 + i;
    int b = r / CC, c = r - b * CC;
    float4 o;
    o.x = 2.f * (acc[i][0] + b1.x + b2.x);
    o.y = 2.f * (acc[i][1] + b1.y + b2.y);
    o.z = 2.f * (acc[i][2] + b1.z + b2.z);
    o.w = 2.f * (acc[i][3] + b1.w + b2.w);
    *(float4*)(xp + ((size_t)b * TT + s * CC + c) * HH + tx4) = o;
  }
}

// ---------------------------------------------------------------------------
// Kernel 2: recurrence + fused head. One block (one wave) per batch element.
// Broadcast of h via LDS row (16 uniform-address ds_read_b128, conflict-free,
// 17 DS ops/step). The float4 hv[16] array + sched_barrier(0) FORCES all 16
// read results live across the barrier -> compiler must issue them
// back-to-back with one lgkmcnt, paying LDS latency ONCE per step.
// (R1-R4 post-mortem: VGPR stuck at 88 => reads batched, latency paid ~5x.)
// W and xp are pre-scaled by 2 so the accumulator is 2z directly.
// ---------------------------------------------------------------------------
__global__ __launch_bounds__(64, 1) void rnn_kernel(
    const float* __restrict__ xp, const float* __restrict__ W_hh,
    const float* __restrict__ fc_w, const float* __restrict__ fc_b,
    float* __restrict__ y) {
  __shared__ float hist[CC][68];
  const int b = blockIdx.x;
  const int lane = threadIdx.x;

  hist[CC - 1][lane] = 0.f;  // h0 = 0 for s=0,c=0 (reads hist[CC-1])

  float W[64];
  for (int s = 0; s < SS; ++s) {
    const float* wr = W_hh + ((size_t)s * HH + lane) * HH;
#pragma unroll
    for (int j = 0; j < 64; j += 4) {
      float4 v = *(const float4*)(wr + j);
      W[j] = 2.f * v.x; W[j + 1] = 2.f * v.y;
      W[j + 2] = 2.f * v.z; W[j + 3] = 2.f * v.w;
    }
    const float* xps = xp + ((size_t)b * TT + s * CC) * HH + lane;

    float xq0 = xps[0 * HH];
    float xq1 = xps[1 * HH];
    float xq2 = xps[2 * HH];
    float xq3 = xps[3 * HH];

    for (int c4 = 0; c4 < 25; ++c4) {
#pragma unroll
      for (int u = 0; u < 4; ++u) {
        const int c = c4 * 4 + u;
        const int cp = (c == 0) ? CC - 1 : c - 1;
        const float xv = (u == 0) ? xq0 : (u == 1) ? xq1 : (u == 2) ? xq2 : xq3;
        // broadcast read: all 16 results forced live across the barrier
        float4 hv[16];
#pragma unroll
        for (int j4 = 0; j4 < 16; ++j4)
          hv[j4] = *(const float4*)&hist[cp][j4 * 4];
        __builtin_amdgcn_sched_barrier(0);
        float a0 = xv, a1 = 0.f, a2 = 0.f, a3 = 0.f;
#pragma unroll
        for (int j4 = 0; j4 < 16; ++j4) {
          a0 += W[j4 * 4 + 0] * hv[j4].x;
          a1 += W[j4 * 4 + 1] * hv[j4].y;
          a2 += W[j4 * 4 + 2] * hv[j4].z;
          a3 += W[j4 * 4 + 3] * hv[j4].w;
        }
        float z2 = (a0 + a1) + (a2 + a3);  // = 2z (pre-scaled)
        float e = __expf(z2);              // exp(2z)
        float h = 1.f - 2.f * __builtin_amdgcn_rcpf(e + 1.f);
        hist[c][lane] = h;
        // reload this slot for step c+4 (off the serial chain)
        if (c4 < 24) {
          const float xn = xps[(c + 4) * HH];
          if (u == 0) xq0 = xn;
          else if (u == 1) xq1 = xn;
          else if (u == 2) xq2 = xn;
          else xq3 = xn;
        }
      }
    }

    // fused head for this segment: lane l -> y[b, s*CC + l]
    const float fb = fc_b[s];
    const float* fw = fc_w + s * HH;  // wave-uniform -> scalar loads
#pragma unroll
    for (int base = 0; base < CC; base += 64) {
      int l = base + lane;
      if (l < CC) {
        float z = fb;
#pragma unroll
        for (int i = 0; i < 64; i += 4) {
          float4 hv = *(const float4*)&hist[l][i];
          z += hv.x * fw[i] + hv.y * fw[i + 1] + hv.z * fw[i + 2] +
               hv.w * fw[i + 3];
        }
        y[(size_t)b * TT + s * CC + l] =
            __builtin_amdgcn_rcpf(1.f + __expf(-z));
      }
    }
  }
}

extern "C" void kernel_launch(void* const* d_in, const int* in_sizes, int n_in,
                              void* d_out, int out_size, void* d_ws,
                              size_t ws_size, hipStream_t stream) {
  const float* x    = (const float*)d_in[0];
  const float* W_ih = (const float*)d_in[1];
  const float* W_hh = (const float*)d_in[2];
  const float* b_ih = (const float*)d_in[3];
  const float* b_hh = (const float*)d_in[4];
  const float* fc_w = (const float*)d_in[5];
  const float* fc_b = (const float*)d_in[6];
  float* y  = (float*)d_out;
  float* xp = (float*)d_ws;  // [B][T][H] fp32 = 65.5 MB

  proj_kernel<<<dim3(400, 10), 256, 0, stream>>>(x, W_ih, b_ih, b_hh, xp);
  rnn_kernel<<<256, 64, 0, stream>>>(xp, W_hh, fc_w, fc_b, y);
}